// Round 10
// baseline (174.275 us; speedup 1.0000x reference)
//
#include <hip/hip_runtime.h>
#include <hip/hip_bf16.h>
#include <hip/hip_cooperative_groups.h>

namespace cg = cooperative_groups;

typedef __attribute__((ext_vector_type(8))) short bf16x8;
typedef __attribute__((ext_vector_type(8))) int i32x8;
typedef __attribute__((ext_vector_type(4))) float f32x4;
typedef unsigned int uint;

#define NROWS 8192
#define F_DIM 128
#define Q_DIM 64
#define KPAD  224   // 193 padded to 7*32
#define H_DIM 256

static __device__ inline unsigned short bf_bits(__hip_bfloat16 b) {
  unsigned short u; __builtin_memcpy(&u, &b, 2); return u;
}
static __device__ inline uint packhl(float v) {
  __hip_bfloat16 h = __float2bfloat16(v);
  float hf = __bfloat162float(h);
  __hip_bfloat16 l = __float2bfloat16(v - hf);
  return ((uint)bf_bits(l) << 16) | (uint)bf_bits(h);
}
static __device__ inline void split_hl(float v, unsigned short& h, unsigned short& l) {
  __hip_bfloat16 hb = __float2bfloat16(v);
  float hf = __bfloat162float(hb);
  __hip_bfloat16 lb = __float2bfloat16(v - hf);
  h = bf_bits(hb); l = bf_bits(lb);
}

union uu { uint4 u; bf16x8 v; };

// One cooperative kernel, 256 blocks x 256 threads (1 block/CU -> co-residency
// guaranteed; 512 failed: cooperative grid > max co-resident).
// Phase A: norm->fp8 (32 rows/block), weight hi/lo pack (W1 row bid + W2 row
// bid per block), cnt zero. Phase B: 2080 gram tiles striped (~8/block).
// Phase C: fused 2-layer MLP + W3 dot, 32 rows/block, direct out write.
__global__ __launch_bounds__(256, 2) void mega_kernel(const float* __restrict__ x,
                                                      const float* __restrict__ q,
                                                      const float* __restrict__ W1,
                                                      const float* __restrict__ b1,
                                                      const float* __restrict__ W2,
                                                      const float* __restrict__ b2,
                                                      const float* __restrict__ W3,
                                                      const float* __restrict__ b3,
                                                      unsigned char* __restrict__ xn8,
                                                      uint* __restrict__ W1P,
                                                      uint* __restrict__ W2P,
                                                      int* __restrict__ cnt,
                                                      float* __restrict__ out) {
  __shared__ char smem[65536];
  cg::grid_group grid = cg::this_grid();
  int tid = threadIdx.x;
  int bid = blockIdx.x;
  int lane = tid & 63;
  int wv = tid >> 6;
  int lr = lane & 15;
  int quad = lane >> 4;

  // ================= phase A: norm -> fp8, weight pack, cnt zero ==========
  {
    int row = bid * 32 + (tid >> 3);
    int sub = tid & 7;                        // 8 threads per row, 16 floats each
    const float4* xp = (const float4*)(x + (size_t)row * F_DIM) + sub * 4;
    float4 v0 = xp[0], v1 = xp[1], v2 = xp[2], v3 = xp[3];
    float s = v0.x * v0.x + v0.y * v0.y + v0.z * v0.z + v0.w * v0.w
            + v1.x * v1.x + v1.y * v1.y + v1.z * v1.z + v1.w * v1.w
            + v2.x * v2.x + v2.y * v2.y + v2.z * v2.z + v2.w * v2.w
            + v3.x * v3.x + v3.y * v3.y + v3.z * v3.z + v3.w * v3.w;
    s += __shfl_xor(s, 1); s += __shfl_xor(s, 2); s += __shfl_xor(s, 4);
    float inv = 1.0f / (sqrtf(s) + 1e-12f);
    int w0 = __builtin_amdgcn_cvt_pk_fp8_f32(v0.x * inv, v0.y * inv, 0, 0);
    w0 = __builtin_amdgcn_cvt_pk_fp8_f32(v0.z * inv, v0.w * inv, w0, 1);
    int w1 = __builtin_amdgcn_cvt_pk_fp8_f32(v1.x * inv, v1.y * inv, 0, 0);
    w1 = __builtin_amdgcn_cvt_pk_fp8_f32(v1.z * inv, v1.w * inv, w1, 1);
    int w2 = __builtin_amdgcn_cvt_pk_fp8_f32(v2.x * inv, v2.y * inv, 0, 0);
    w2 = __builtin_amdgcn_cvt_pk_fp8_f32(v2.z * inv, v2.w * inv, w2, 1);
    int w3 = __builtin_amdgcn_cvt_pk_fp8_f32(v3.x * inv, v3.y * inv, 0, 0);
    w3 = __builtin_amdgcn_cvt_pk_fp8_f32(v3.z * inv, v3.w * inv, w3, 1);
    uint4 pk; pk.x = (uint)w0; pk.y = (uint)w1; pk.z = (uint)w2; pk.w = (uint)w3;
    *(uint4*)(xn8 + (size_t)row * F_DIM + sub * 16) = pk;

    // weight pack: block bid handles W1 row bid and W2 row bid
    if (tid < KPAD) W1P[bid * KPAD + tid] = (tid < 193) ? packhl(W1[bid * 193 + tid]) : 0u;
    W2P[bid * 256 + tid] = packhl(W2[bid * 256 + tid]);
    if (bid < 32) cnt[bid * 256 + tid] = 0;
  }

  grid.sync();

  // ================= phase B: gram tiles =================================
  for (int t = bid; t < 2080; t += 256) {
    int bi = (int)((129.0f - sqrtf(129.0f * 129.0f - 8.0f * (float)t)) * 0.5f);
    while ((bi + 1) * (129 - (bi + 1)) / 2 <= t) bi++;
    while (bi * (129 - bi) / 2 > t) bi--;
    int bj = bi + (t - bi * (129 - bi) / 2);
    int i0 = bi * 128, j0 = bj * 128;

    __syncthreads();   // protect smem from previous task's readers
#pragma unroll
    for (int it = 0; it < 8; ++it) {
      int half = it >> 2;
      int row = (it & 3) * 32 + (tid >> 3);
      int chunk = tid & 7;
      int grow = (half ? j0 : i0) + row;
      uint4 v = *(const uint4*)(xn8 + (size_t)grow * F_DIM + chunk * 16);
      *(uint4*)(smem + half * 16384 + row * 128 + ((chunk ^ (row & 7)) << 4)) = v;
    }
    __syncthreads();

    int wi = (wv >> 1) * 64, wj = (wv & 1) * 64;

    i32x8 a[4], b[4];
#pragma unroll
    for (int tt = 0; tt < 4; tt++) {
      int r = wi + tt * 16 + lr;
      const char* base = smem + r * 128;
      uint4 lo = *(const uint4*)(base + (((2 * quad) ^ (r & 7)) << 4));
      uint4 hi = *(const uint4*)(base + (((2 * quad + 1) ^ (r & 7)) << 4));
      i32x8 f;
      f[0] = lo.x; f[1] = lo.y; f[2] = lo.z; f[3] = lo.w;
      f[4] = hi.x; f[5] = hi.y; f[6] = hi.z; f[7] = hi.w;
      a[tt] = f;
    }
#pragma unroll
    for (int tt = 0; tt < 4; tt++) {
      int r = wj + tt * 16 + lr;
      const char* base = smem + 16384 + r * 128;
      uint4 lo = *(const uint4*)(base + (((2 * quad) ^ (r & 7)) << 4));
      uint4 hi = *(const uint4*)(base + (((2 * quad + 1) ^ (r & 7)) << 4));
      i32x8 f;
      f[0] = lo.x; f[1] = lo.y; f[2] = lo.z; f[3] = lo.w;
      f[4] = hi.x; f[5] = hi.y; f[6] = hi.z; f[7] = hi.w;
      b[tt] = f;
    }

    f32x4 acc[4][4];
#pragma unroll
    for (int i = 0; i < 4; i++)
#pragma unroll
      for (int j = 0; j < 4; j++) acc[i][j] = (f32x4){0.f, 0.f, 0.f, 0.f};

#pragma unroll
    for (int tr = 0; tr < 4; tr++)
#pragma unroll
      for (int tc = 0; tc < 4; tc++)
        acc[tr][tc] = __builtin_amdgcn_mfma_scale_f32_16x16x128_f8f6f4(
            a[tr], b[tc], acc[tr][tc], 0, 0, 0, 0x7f7f7f7f, 0, 0x7f7f7f7f);

    int i_base = i0 + wi, j_base = j0 + wj;
    bool diag_wave = (i_base == j_base);
    bool offdiag_block = (bi != bj);

    float mx = 0.f;
#pragma unroll
    for (int tr = 0; tr < 4; tr++)
#pragma unroll
      for (int tc = 0; tc < 4; tc++)
#pragma unroll
        for (int r = 0; r < 4; r++) {
          float v = acc[tr][tc][r];
          if (diag_wave && tr == tc && lr == quad * 4 + r) v = 0.f;
          mx = fmaxf(mx, fabsf(v));
        }
    if (__any(mx >= 0.9746f)) {
      for (int tr = 0; tr < 4; tr++)
        for (int tc = 0; tc < 4; tc++)
          for (int r = 0; r < 4; r++) {
            float v = acc[tr][tc][r];
            int row = i_base + tr * 16 + quad * 4 + r;
            int col = j_base + tc * 16 + lr;
            if (v * v >= 0.95f && row != col) {
              atomicAdd(&cnt[row], 1);
              if (offdiag_block) atomicAdd(&cnt[col], 1);
            }
          }
    }
  }

  grid.sync();

  // ================= phase C: fused MLP, 32 rows/block ====================
  {
    short* Ahs = (short*)smem;                 // [32][232] hi  (14848 B)
    short* Als = (short*)(smem + 14848);       // [32][232] lo
    uint*  H1  = (uint*)smem;                  // [32][256] packed, overlays A
    uint*  Bx  = (uint*)(smem + 32768);        // [256][32] packed
    float* part = (float*)(smem + 32768);      // [4][32], overlays Bx
    int mb = bid * 32;

    // A stage: feats[32][224] hi/lo from x, q, cnt
    {
      int r = tid >> 3;
      int c8 = (tid & 7) * 4;
#pragma unroll
      for (int it = 0; it < 7; ++it) {
        int col = it * 32 + c8;
        float4 v = {0.f, 0.f, 0.f, 0.f};
        if (it < 4)      v = *(const float4*)(x + (size_t)(mb + r) * F_DIM + col);
        else if (it < 6) v = *(const float4*)(q + (size_t)(mb + r) * Q_DIM + (col - 128));
        else if (c8 == 0) v.x = (float)cnt[mb + r] * (1.0f / 8192.0f);
        unsigned short h0, l0, h1, l1, h2, l2, h3, l3;
        split_hl(v.x, h0, l0); split_hl(v.y, h1, l1);
        split_hl(v.z, h2, l2); split_hl(v.w, h3, l3);
        *(uint2*)&Ahs[r * 232 + col] = (uint2){(uint)h0 | ((uint)h1 << 16), (uint)h2 | ((uint)h3 << 16)};
        *(uint2*)&Als[r * 232 + col] = (uint2){(uint)l0 | ((uint)l1 << 16), (uint)l2 | ((uint)l3 << 16)};
      }
    }

    f32x4 acc[2][4];
#pragma unroll
    for (int i = 0; i < 2; i++)
#pragma unroll
      for (int j = 0; j < 4; j++) acc[i][j] = (f32x4){0.f, 0.f, 0.f, 0.f};

    // phase 1: h1 = relu(feats @ W1^T + b1), K = 224
    for (int kc = 0; kc < 7; ++kc) {
      int k0 = kc * 32;
      __syncthreads();
#pragma unroll
      for (int i = 0; i < 8; ++i) {
        int flat = i * 256 + tid;
        int n = flat >> 3, j = flat & 7;
        uint4 w = *(const uint4*)(W1P + (size_t)n * KPAD + k0 + j * 4);
        *(uint4*)&Bx[n * 32 + ((j ^ (n & 7)) * 4)] = w;
      }
      __syncthreads();
      bf16x8 ah[2], al[2], bh[4], bl[4];
#pragma unroll
      for (int tt = 0; tt < 2; ++tt) {
        int row = tt * 16 + lr;
        ah[tt] = *(const bf16x8*)&Ahs[row * 232 + k0 + quad * 8];
        al[tt] = *(const bf16x8*)&Als[row * 232 + k0 + quad * 8];
      }
#pragma unroll
      for (int tc = 0; tc < 4; ++tc) {
        int n = wv * 64 + tc * 16 + lr;
        uint4 u0 = *(const uint4*)&Bx[n * 32 + (((quad * 2) ^ (n & 7)) * 4)];
        uint4 u1 = *(const uint4*)&Bx[n * 32 + (((quad * 2 + 1) ^ (n & 7)) * 4)];
        uu h, l;
        h.u.x = (u0.x & 0xffffu) | (u0.y << 16);
        h.u.y = (u0.z & 0xffffu) | (u0.w << 16);
        h.u.z = (u1.x & 0xffffu) | (u1.y << 16);
        h.u.w = (u1.z & 0xffffu) | (u1.w << 16);
        l.u.x = (u0.x >> 16) | (u0.y & 0xffff0000u);
        l.u.y = (u0.z >> 16) | (u0.w & 0xffff0000u);
        l.u.z = (u1.x >> 16) | (u1.y & 0xffff0000u);
        l.u.w = (u1.z >> 16) | (u1.w & 0xffff0000u);
        bh[tc] = h.v; bl[tc] = l.v;
      }
#pragma unroll
      for (int tt = 0; tt < 2; ++tt)
#pragma unroll
        for (int tc = 0; tc < 4; ++tc) {
          acc[tt][tc] = __builtin_amdgcn_mfma_f32_16x16x32_bf16(ah[tt], bh[tc], acc[tt][tc], 0, 0, 0);
          acc[tt][tc] = __builtin_amdgcn_mfma_f32_16x16x32_bf16(ah[tt], bl[tc], acc[tt][tc], 0, 0, 0);
          acc[tt][tc] = __builtin_amdgcn_mfma_f32_16x16x32_bf16(al[tt], bh[tc], acc[tt][tc], 0, 0, 0);
        }
    }

    __syncthreads();   // all A reads done before H1 overlays A
    // phase-1 epilogue: relu+bias -> H1 (packed, swizzled)
#pragma unroll
    for (int tc = 0; tc < 4; ++tc) {
      int n = wv * 64 + tc * 16 + lr;
      float bv = b1[n];
      int g = n >> 2, jj = n & 3;
#pragma unroll
      for (int tt = 0; tt < 2; ++tt)
#pragma unroll
        for (int r = 0; r < 4; ++r) {
          int row = tt * 16 + quad * 4 + r;
          float v = fmaxf(acc[tt][tc][r] + bv, 0.f);
          H1[row * 256 + ((g ^ (row & 31)) * 4 + jj)] = packhl(v);
        }
    }
#pragma unroll
    for (int i = 0; i < 2; i++)
#pragma unroll
      for (int j = 0; j < 4; j++) acc[i][j] = (f32x4){0.f, 0.f, 0.f, 0.f};

    // phase 2: h2 = relu(h1 @ W2^T + b2), K = 256
    for (int kc = 0; kc < 8; ++kc) {
      int k0 = kc * 32;
      __syncthreads();
#pragma unroll
      for (int i = 0; i < 8; ++i) {
        int flat = i * 256 + tid;
        int n = flat >> 3, j = flat & 7;
        uint4 w = *(const uint4*)(W2P + (size_t)n * 256 + k0 + j * 4);
        *(uint4*)&Bx[n * 32 + ((j ^ (n & 7)) * 4)] = w;
      }
      __syncthreads();
      bf16x8 ah[2], al[2], bh[4], bl[4];
#pragma unroll
      for (int tt = 0; tt < 2; ++tt) {
        int row = tt * 16 + lr;
        int cb = kc * 8 + quad * 2;
        uint4 u0 = *(const uint4*)&H1[row * 256 + ((cb ^ (row & 31)) * 4)];
        uint4 u1 = *(const uint4*)&H1[row * 256 + (((cb + 1) ^ (row & 31)) * 4)];
        uu h, l;
        h.u.x = (u0.x & 0xffffu) | (u0.y << 16);
        h.u.y = (u0.z & 0xffffu) | (u0.w << 16);
        h.u.z = (u1.x & 0xffffu) | (u1.y << 16);
        h.u.w = (u1.z & 0xffffu) | (u1.w << 16);
        l.u.x = (u0.x >> 16) | (u0.y & 0xffff0000u);
        l.u.y = (u0.z >> 16) | (u0.w & 0xffff0000u);
        l.u.z = (u1.x >> 16) | (u1.y & 0xffff0000u);
        l.u.w = (u1.z >> 16) | (u1.w & 0xffff0000u);
        ah[tt] = h.v; al[tt] = l.v;
      }
#pragma unroll
      for (int tc = 0; tc < 4; ++tc) {
        int n = wv * 64 + tc * 16 + lr;
        uint4 u0 = *(const uint4*)&Bx[n * 32 + (((quad * 2) ^ (n & 7)) * 4)];
        uint4 u1 = *(const uint4*)&Bx[n * 32 + (((quad * 2 + 1) ^ (n & 7)) * 4)];
        uu h, l;
        h.u.x = (u0.x & 0xffffu) | (u0.y << 16);
        h.u.y = (u0.z & 0xffffu) | (u0.w << 16);
        h.u.z = (u1.x & 0xffffu) | (u1.y << 16);
        h.u.w = (u1.z & 0xffffu) | (u1.w << 16);
        l.u.x = (u0.x >> 16) | (u0.y & 0xffff0000u);
        l.u.y = (u0.z >> 16) | (u0.w & 0xffff0000u);
        l.u.z = (u1.x >> 16) | (u1.y & 0xffff0000u);
        l.u.w = (u1.z >> 16) | (u1.w & 0xffff0000u);
        bh[tc] = h.v; bl[tc] = l.v;
      }
#pragma unroll
      for (int tt = 0; tt < 2; ++tt)
#pragma unroll
        for (int tc = 0; tc < 4; ++tc) {
          acc[tt][tc] = __builtin_amdgcn_mfma_f32_16x16x32_bf16(ah[tt], bh[tc], acc[tt][tc], 0, 0, 0);
          acc[tt][tc] = __builtin_amdgcn_mfma_f32_16x16x32_bf16(ah[tt], bl[tc], acc[tt][tc], 0, 0, 0);
          acc[tt][tc] = __builtin_amdgcn_mfma_f32_16x16x32_bf16(al[tt], bh[tc], acc[tt][tc], 0, 0, 0);
        }
    }

    // epilogue: relu+bias, dot W3, lane reduce, cross-wave reduce, store
    float s[2][4];
#pragma unroll
    for (int tt = 0; tt < 2; ++tt)
#pragma unroll
      for (int r = 0; r < 4; ++r) s[tt][r] = 0.f;
#pragma unroll
    for (int tc = 0; tc < 4; ++tc) {
      int n = wv * 64 + tc * 16 + lr;
      float bv = b2[n];
      float w3 = W3[n];
#pragma unroll
      for (int tt = 0; tt < 2; ++tt)
#pragma unroll
        for (int r = 0; r < 4; ++r)
          s[tt][r] += fmaxf(acc[tt][tc][r] + bv, 0.f) * w3;
    }
#pragma unroll
    for (int tt = 0; tt < 2; ++tt)
#pragma unroll
      for (int r = 0; r < 4; ++r) {
        s[tt][r] += __shfl_xor(s[tt][r], 1);
        s[tt][r] += __shfl_xor(s[tt][r], 2);
        s[tt][r] += __shfl_xor(s[tt][r], 4);
        s[tt][r] += __shfl_xor(s[tt][r], 8);
      }
    __syncthreads();   // all Bx reads done before part overlays Bx
    if (lr == 0) {
#pragma unroll
      for (int tt = 0; tt < 2; ++tt)
#pragma unroll
        for (int r = 0; r < 4; ++r)
          part[wv * 32 + tt * 16 + quad * 4 + r] = s[tt][r];
    }
    __syncthreads();
    if (tid < 32)
      out[mb + tid] = part[tid] + part[32 + tid] + part[64 + tid] + part[96 + tid] + b3[0];
  }
}

extern "C" void kernel_launch(void* const* d_in, const int* in_sizes, int n_in,
                              void* d_out, int out_size, void* d_ws, size_t ws_size,
                              hipStream_t stream) {
  const float* x  = (const float*)d_in[0];
  const float* q  = (const float*)d_in[1];
  const float* W1 = (const float*)d_in[2];
  const float* b1 = (const float*)d_in[3];
  const float* W2 = (const float*)d_in[4];
  const float* b2 = (const float*)d_in[5];
  const float* W3 = (const float*)d_in[6];
  const float* b3 = (const float*)d_in[7];
  float* out = (float*)d_out;

  char* ws = (char*)d_ws;
  unsigned char* xn8 = (unsigned char*)(ws);         // 1 MB
  int*  cnt = (int*)(ws + 0x100000);                 // 32 KB
  uint* W1P = (uint*)(ws + 0x110000);                // 224 KB
  uint* W2P = (uint*)(ws + 0x150000);                // 256 KB

  void* args[] = {(void*)&x, (void*)&q, (void*)&W1, (void*)&b1, (void*)&W2, (void*)&b2,
                  (void*)&W3, (void*)&b3, (void*)&xn8, (void*)&W1P, (void*)&W2P,
                  (void*)&cnt, (void*)&out};
  hipLaunchCooperativeKernel((void*)mega_kernel, dim3(256), dim3(256), args, 0, stream);
}

// Round 11
// 97.840 us; speedup vs baseline: 1.7812x; 1.7812x over previous
//
#include <hip/hip_runtime.h>
#include <hip/hip_bf16.h>

typedef __attribute__((ext_vector_type(8))) short bf16x8;
typedef __attribute__((ext_vector_type(8))) int i32x8;
typedef __attribute__((ext_vector_type(4))) float f32x4;
typedef unsigned int uint;

#define NROWS 8192
#define F_DIM 128
#define Q_DIM 64
#define KPAD  224   // 193 padded to 7*32
#define H_DIM 256

static __device__ inline unsigned short bf_bits(__hip_bfloat16 b) {
  unsigned short u; __builtin_memcpy(&u, &b, 2); return u;
}
static __device__ inline uint packhl(float v) {
  __hip_bfloat16 h = __float2bfloat16(v);
  float hf = __bfloat162float(h);
  __hip_bfloat16 l = __float2bfloat16(v - hf);
  return ((uint)bf_bits(l) << 16) | (uint)bf_bits(h);
}
static __device__ inline void split_hl(float v, unsigned short& h, unsigned short& l) {
  __hip_bfloat16 hb = __float2bfloat16(v);
  float hf = __bfloat162float(hb);
  __hip_bfloat16 lb = __float2bfloat16(v - hf);
  h = bf_bits(hb); l = bf_bits(lb);
}

union uu { uint4 u; bf16x8 v; };

// ---- prep: row norm -> xn8(fp8 e4m3), zero cnt, weight split+pack folded --
// 2048 blocks: each does 4 rows; blocks 0..255 also pack W2 row bid,
// blocks 256..511 also pack W1 row bid-256; blocks 0..31 zero cnt.
__global__ __launch_bounds__(256) void norm_prep_kernel(const float* __restrict__ x,
                                                        const float* __restrict__ W1,
                                                        const float* __restrict__ W2,
                                                        unsigned char* __restrict__ xn8,
                                                        uint* __restrict__ W1P,
                                                        uint* __restrict__ W2P,
                                                        int* __restrict__ cnt) {
  int tid = threadIdx.x;
  int bid = blockIdx.x;
  if (bid < 256) {
    W2P[bid * 256 + tid] = packhl(W2[bid * 256 + tid]);
  } else if (bid < 512) {
    int n = bid - 256;
    if (tid < KPAD) W1P[n * KPAD + tid] = (tid < 193) ? packhl(W1[n * 193 + tid]) : 0u;
  }
  if (bid < 32) cnt[bid * 256 + tid] = 0;

  int lane = tid & 63;
  int row = bid * 4 + (tid >> 6);
  const float2 v = *(const float2*)(x + (size_t)row * F_DIM + lane * 2);
  float s = v.x * v.x + v.y * v.y;
#pragma unroll
  for (int off = 32; off; off >>= 1) s += __shfl_xor(s, off);
  float inv = 1.0f / (sqrtf(s) + 1e-12f);
  int pk = __builtin_amdgcn_cvt_pk_fp8_f32(v.x * inv, v.y * inv, 0, 0);
  *(unsigned short*)(xn8 + (size_t)row * F_DIM + lane * 2) = (unsigned short)(pk & 0xffff);
}

// ---- Gram via MX-fp8 K=128 MFMA + threshold + row-count -------------------
__global__ __launch_bounds__(256) void gram8_kernel(const unsigned char* __restrict__ xn8,
                                                    int* __restrict__ cnt) {
  __shared__ char smem[32768];  // A 16KB + B 16KB; 128B rows, chunk ^ (row&7) swizzle
  int tid = threadIdx.x;
  int lane = tid & 63;
  int wave = tid >> 6;
  int lr = lane & 15;
  int quad = lane >> 4;

  int t = blockIdx.x;
  int bi = (int)((129.0f - sqrtf(129.0f * 129.0f - 8.0f * (float)t)) * 0.5f);
  while ((bi + 1) * (129 - (bi + 1)) / 2 <= t) bi++;
  while (bi * (129 - bi) / 2 > t) bi--;
  int bj = bi + (t - bi * (129 - bi) / 2);
  int i0 = bi * 128, j0 = bj * 128;

#pragma unroll
  for (int it = 0; it < 8; ++it) {
    int half = it >> 2;                    // 0 = A rows (i0), 1 = B rows (j0)
    int row = (it & 3) * 32 + (tid >> 3);
    int chunk = tid & 7;
    int grow = (half ? j0 : i0) + row;
    uint4 v = *(const uint4*)(xn8 + (size_t)grow * F_DIM + chunk * 16);
    *(uint4*)(smem + half * 16384 + row * 128 + ((chunk ^ (row & 7)) << 4)) = v;
  }
  __syncthreads();

  int wi = (wave >> 1) * 64, wj = (wave & 1) * 64;

  f32x4 acc[4][4];
#pragma unroll
  for (int i = 0; i < 4; i++)
#pragma unroll
    for (int j = 0; j < 4; j++) acc[i][j] = (f32x4){0.f, 0.f, 0.f, 0.f};

  i32x8 a[4], b[4];
#pragma unroll
  for (int tt = 0; tt < 4; tt++) {
    int r = wi + tt * 16 + lr;
    const char* base = smem + r * 128;
    uint4 lo = *(const uint4*)(base + (((2 * quad) ^ (r & 7)) << 4));
    uint4 hi = *(const uint4*)(base + (((2 * quad + 1) ^ (r & 7)) << 4));
    i32x8 f;
    f[0] = lo.x; f[1] = lo.y; f[2] = lo.z; f[3] = lo.w;
    f[4] = hi.x; f[5] = hi.y; f[6] = hi.z; f[7] = hi.w;
    a[tt] = f;
  }
#pragma unroll
  for (int tt = 0; tt < 4; tt++) {
    int r = wj + tt * 16 + lr;
    const char* base = smem + 16384 + r * 128;
    uint4 lo = *(const uint4*)(base + (((2 * quad) ^ (r & 7)) << 4));
    uint4 hi = *(const uint4*)(base + (((2 * quad + 1) ^ (r & 7)) << 4));
    i32x8 f;
    f[0] = lo.x; f[1] = lo.y; f[2] = lo.z; f[3] = lo.w;
    f[4] = hi.x; f[5] = hi.y; f[6] = hi.z; f[7] = hi.w;
    b[tt] = f;
  }

#pragma unroll
  for (int tr = 0; tr < 4; tr++)
#pragma unroll
    for (int tc = 0; tc < 4; tc++)
      acc[tr][tc] = __builtin_amdgcn_mfma_scale_f32_16x16x128_f8f6f4(
          a[tr], b[tc], acc[tr][tc], 0, 0, 0, 0x7f7f7f7f, 0, 0x7f7f7f7f);

  int i_base = i0 + wi, j_base = j0 + wj;
  bool diag_wave = (i_base == j_base);
  bool offdiag_block = (bi != bj);

  float mx = 0.f;
#pragma unroll
  for (int tr = 0; tr < 4; tr++)
#pragma unroll
    for (int tc = 0; tc < 4; tc++)
#pragma unroll
      for (int r = 0; r < 4; r++) {
        float v = acc[tr][tc][r];
        if (diag_wave && tr == tc && lr == quad * 4 + r) v = 0.f;
        mx = fmaxf(mx, fabsf(v));
      }
  if (__any(mx >= 0.9746f)) {
    for (int tr = 0; tr < 4; tr++)
      for (int tc = 0; tc < 4; tc++)
        for (int r = 0; r < 4; r++) {
          float v = acc[tr][tc][r];
          int row = i_base + tr * 16 + quad * 4 + r;
          int col = j_base + tc * 16 + lr;
          if (v * v >= 0.95f && row != col) {
            atomicAdd(&cnt[row], 1);
            if (offdiag_block) atomicAdd(&cnt[col], 1);
          }
        }
  }
}

// ---- fused MLP: 32 rows/block, layer1 -> h1 in LDS -> layer2 -> W3 dot ----
// LDS (64 KB exactly): region0 = A hi/lo shorts [32][232]  UNION  H1 packed
// uints [32][256] (16B-chunk XOR swizzle); region1 = B packed uints [256][32]
// (16B-chunk XOR swizzle)  UNION  part[4][32] floats.
__global__ __launch_bounds__(256) void fused_mlp_kernel(const float* __restrict__ x,
                                                        const float* __restrict__ q,
                                                        const uint* __restrict__ W1P,
                                                        const uint* __restrict__ W2P,
                                                        const float* __restrict__ b1,
                                                        const float* __restrict__ b2,
                                                        const float* __restrict__ W3,
                                                        const float* __restrict__ b3,
                                                        const int* __restrict__ cnt,
                                                        float* __restrict__ out) {
  __shared__ char smem[65536];
  short* Ahs = (short*)smem;                 // [32][232] hi  (14848 B)
  short* Als = (short*)(smem + 14848);       // [32][232] lo
  uint*  H1  = (uint*)smem;                  // [32][256] packed, overlays A
  uint*  Bx  = (uint*)(smem + 32768);        // [256][32] packed
  float* part = (float*)(smem + 32768);      // [4][32], overlays Bx

  int tid = threadIdx.x;
  int lane = tid & 63;
  int wv = tid >> 6;
  int lr = lane & 15;
  int quad = lane >> 4;
  int mb = blockIdx.x * 32;

  // ---- A stage: feats[32][224] hi/lo from x, q, cnt ----
  {
    int r = tid >> 3;
    int c8 = (tid & 7) * 4;
#pragma unroll
    for (int it = 0; it < 7; ++it) {
      int col = it * 32 + c8;
      float4 v = {0.f, 0.f, 0.f, 0.f};
      if (it < 4)      v = *(const float4*)(x + (size_t)(mb + r) * F_DIM + col);
      else if (it < 6) v = *(const float4*)(q + (size_t)(mb + r) * Q_DIM + (col - 128));
      else if (c8 == 0) v.x = (float)cnt[mb + r] * (1.0f / 8192.0f);
      unsigned short h0, l0, h1, l1, h2, l2, h3, l3;
      split_hl(v.x, h0, l0); split_hl(v.y, h1, l1);
      split_hl(v.z, h2, l2); split_hl(v.w, h3, l3);
      *(uint2*)&Ahs[r * 232 + col] = (uint2){(uint)h0 | ((uint)h1 << 16), (uint)h2 | ((uint)h3 << 16)};
      *(uint2*)&Als[r * 232 + col] = (uint2){(uint)l0 | ((uint)l1 << 16), (uint)l2 | ((uint)l3 << 16)};
    }
  }

  f32x4 acc[2][4];
#pragma unroll
  for (int i = 0; i < 2; i++)
#pragma unroll
    for (int j = 0; j < 4; j++) acc[i][j] = (f32x4){0.f, 0.f, 0.f, 0.f};

  // ---- phase 1: h1 = relu(feats @ W1^T + b1), K = 224 ----
  for (int kc = 0; kc < 7; ++kc) {
    int k0 = kc * 32;
    __syncthreads();
#pragma unroll
    for (int i = 0; i < 8; ++i) {
      int flat = i * 256 + tid;
      int n = flat >> 3, j = flat & 7;
      uint4 w = *(const uint4*)(W1P + (size_t)n * KPAD + k0 + j * 4);
      *(uint4*)&Bx[n * 32 + ((j ^ (n & 7)) * 4)] = w;
    }
    __syncthreads();
    bf16x8 ah[2], al[2], bh[4], bl[4];
#pragma unroll
    for (int tt = 0; tt < 2; ++tt) {
      int row = tt * 16 + lr;
      ah[tt] = *(const bf16x8*)&Ahs[row * 232 + k0 + quad * 8];
      al[tt] = *(const bf16x8*)&Als[row * 232 + k0 + quad * 8];
    }
#pragma unroll
    for (int tc = 0; tc < 4; ++tc) {
      int n = wv * 64 + tc * 16 + lr;
      uint4 u0 = *(const uint4*)&Bx[n * 32 + (((quad * 2) ^ (n & 7)) * 4)];
      uint4 u1 = *(const uint4*)&Bx[n * 32 + (((quad * 2 + 1) ^ (n & 7)) * 4)];
      uu h, l;
      h.u.x = (u0.x & 0xffffu) | (u0.y << 16);
      h.u.y = (u0.z & 0xffffu) | (u0.w << 16);
      h.u.z = (u1.x & 0xffffu) | (u1.y << 16);
      h.u.w = (u1.z & 0xffffu) | (u1.w << 16);
      l.u.x = (u0.x >> 16) | (u0.y & 0xffff0000u);
      l.u.y = (u0.z >> 16) | (u0.w & 0xffff0000u);
      l.u.z = (u1.x >> 16) | (u1.y & 0xffff0000u);
      l.u.w = (u1.z >> 16) | (u1.w & 0xffff0000u);
      bh[tc] = h.v; bl[tc] = l.v;
    }
#pragma unroll
    for (int tt = 0; tt < 2; ++tt)
#pragma unroll
      for (int tc = 0; tc < 4; ++tc) {
        acc[tt][tc] = __builtin_amdgcn_mfma_f32_16x16x32_bf16(ah[tt], bh[tc], acc[tt][tc], 0, 0, 0);
        acc[tt][tc] = __builtin_amdgcn_mfma_f32_16x16x32_bf16(ah[tt], bl[tc], acc[tt][tc], 0, 0, 0);
        acc[tt][tc] = __builtin_amdgcn_mfma_f32_16x16x32_bf16(al[tt], bh[tc], acc[tt][tc], 0, 0, 0);
      }
  }

  __syncthreads();   // all A reads done before H1 overlays A
  // ---- phase-1 epilogue: relu+bias -> H1 (packed, swizzled) ----
#pragma unroll
  for (int tc = 0; tc < 4; ++tc) {
    int n = wv * 64 + tc * 16 + lr;
    float bv = b1[n];
    int g = n >> 2, jj = n & 3;
#pragma unroll
    for (int tt = 0; tt < 2; ++tt)
#pragma unroll
      for (int r = 0; r < 4; ++r) {
        int row = tt * 16 + quad * 4 + r;
        float v = fmaxf(acc[tt][tc][r] + bv, 0.f);
        H1[row * 256 + ((g ^ (row & 31)) * 4 + jj)] = packhl(v);
      }
  }
#pragma unroll
  for (int i = 0; i < 2; i++)
#pragma unroll
    for (int j = 0; j < 4; j++) acc[i][j] = (f32x4){0.f, 0.f, 0.f, 0.f};

  // ---- phase 2: h2 = relu(h1 @ W2^T + b2), K = 256 ----
  for (int kc = 0; kc < 8; ++kc) {
    int k0 = kc * 32;
    __syncthreads();
#pragma unroll
    for (int i = 0; i < 8; ++i) {
      int flat = i * 256 + tid;
      int n = flat >> 3, j = flat & 7;
      uint4 w = *(const uint4*)(W2P + (size_t)n * 256 + k0 + j * 4);
      *(uint4*)&Bx[n * 32 + ((j ^ (n & 7)) * 4)] = w;
    }
    __syncthreads();
    bf16x8 ah[2], al[2], bh[4], bl[4];
#pragma unroll
    for (int tt = 0; tt < 2; ++tt) {
      int row = tt * 16 + lr;
      int cb = kc * 8 + quad * 2;
      uint4 u0 = *(const uint4*)&H1[row * 256 + ((cb ^ (row & 31)) * 4)];
      uint4 u1 = *(const uint4*)&H1[row * 256 + (((cb + 1) ^ (row & 31)) * 4)];
      uu h, l;
      h.u.x = (u0.x & 0xffffu) | (u0.y << 16);
      h.u.y = (u0.z & 0xffffu) | (u0.w << 16);
      h.u.z = (u1.x & 0xffffu) | (u1.y << 16);
      h.u.w = (u1.z & 0xffffu) | (u1.w << 16);
      l.u.x = (u0.x >> 16) | (u0.y & 0xffff0000u);
      l.u.y = (u0.z >> 16) | (u0.w & 0xffff0000u);
      l.u.z = (u1.x >> 16) | (u1.y & 0xffff0000u);
      l.u.w = (u1.z >> 16) | (u1.w & 0xffff0000u);
      ah[tt] = h.v; al[tt] = l.v;
    }
#pragma unroll
    for (int tc = 0; tc < 4; ++tc) {
      int n = wv * 64 + tc * 16 + lr;
      uint4 u0 = *(const uint4*)&Bx[n * 32 + (((quad * 2) ^ (n & 7)) * 4)];
      uint4 u1 = *(const uint4*)&Bx[n * 32 + (((quad * 2 + 1) ^ (n & 7)) * 4)];
      uu h, l;
      h.u.x = (u0.x & 0xffffu) | (u0.y << 16);
      h.u.y = (u0.z & 0xffffu) | (u0.w << 16);
      h.u.z = (u1.x & 0xffffu) | (u1.y << 16);
      h.u.w = (u1.z & 0xffffu) | (u1.w << 16);
      l.u.x = (u0.x >> 16) | (u0.y & 0xffff0000u);
      l.u.y = (u0.z >> 16) | (u0.w & 0xffff0000u);
      l.u.z = (u1.x >> 16) | (u1.y & 0xffff0000u);
      l.u.w = (u1.z >> 16) | (u1.w & 0xffff0000u);
      bh[tc] = h.v; bl[tc] = l.v;
    }
#pragma unroll
    for (int tt = 0; tt < 2; ++tt)
#pragma unroll
      for (int tc = 0; tc < 4; ++tc) {
        acc[tt][tc] = __builtin_amdgcn_mfma_f32_16x16x32_bf16(ah[tt], bh[tc], acc[tt][tc], 0, 0, 0);
        acc[tt][tc] = __builtin_amdgcn_mfma_f32_16x16x32_bf16(ah[tt], bl[tc], acc[tt][tc], 0, 0, 0);
        acc[tt][tc] = __builtin_amdgcn_mfma_f32_16x16x32_bf16(al[tt], bh[tc], acc[tt][tc], 0, 0, 0);
      }
  }

  // ---- phase-2 epilogue: relu+bias, dot W3, cross-wave reduce, store ----
  float s[2][4];
#pragma unroll
  for (int tt = 0; tt < 2; ++tt)
#pragma unroll
    for (int r = 0; r < 4; ++r) s[tt][r] = 0.f;
#pragma unroll
  for (int tc = 0; tc < 4; ++tc) {
    int n = wv * 64 + tc * 16 + lr;
    float bv = b2[n];
    float w3 = W3[n];
#pragma unroll
    for (int tt = 0; tt < 2; ++tt)
#pragma unroll
      for (int r = 0; r < 4; ++r)
        s[tt][r] += fmaxf(acc[tt][tc][r] + bv, 0.f) * w3;
  }
#pragma unroll
  for (int tt = 0; tt < 2; ++tt)
#pragma unroll
    for (int r = 0; r < 4; ++r) {
      s[tt][r] += __shfl_xor(s[tt][r], 1);
      s[tt][r] += __shfl_xor(s[tt][r], 2);
      s[tt][r] += __shfl_xor(s[tt][r], 4);
      s[tt][r] += __shfl_xor(s[tt][r], 8);
    }
  __syncthreads();   // all Bx reads done before part overlays Bx
  if (lr == 0) {
#pragma unroll
    for (int tt = 0; tt < 2; ++tt)
#pragma unroll
      for (int r = 0; r < 4; ++r)
        part[wv * 32 + tt * 16 + quad * 4 + r] = s[tt][r];
  }
  __syncthreads();
  if (tid < 32)
    out[mb + tid] = part[tid] + part[32 + tid] + part[64 + tid] + part[96 + tid] + b3[0];
}

extern "C" void kernel_launch(void* const* d_in, const int* in_sizes, int n_in,
                              void* d_out, int out_size, void* d_ws, size_t ws_size,
                              hipStream_t stream) {
  const float* x  = (const float*)d_in[0];
  const float* q  = (const float*)d_in[1];
  const float* W1 = (const float*)d_in[2];
  const float* b1 = (const float*)d_in[3];
  const float* W2 = (const float*)d_in[4];
  const float* b2 = (const float*)d_in[5];
  const float* W3 = (const float*)d_in[6];
  const float* b3 = (const float*)d_in[7];
  float* out = (float*)d_out;

  char* ws = (char*)d_ws;
  unsigned char* xn8 = (unsigned char*)(ws);         // 1 MB
  int*  cnt = (int*)(ws + 0x100000);                 // 32 KB
  uint* W1P = (uint*)(ws + 0x110000);                // 224 KB
  uint* W2P = (uint*)(ws + 0x150000);                // 256 KB

  norm_prep_kernel<<<dim3(2048), dim3(256), 0, stream>>>(x, W1, W2, xn8, W1P, W2P, cnt);
  gram8_kernel<<<dim3(2080), dim3(256), 0, stream>>>(xn8, cnt);
  fused_mlp_kernel<<<dim3(256), dim3(256), 0, stream>>>(x, q, W1P, W2P, b1, b2, W3, b3, cnt, out);
}